// Round 10
// baseline (2045.747 us; speedup 1.0000x reference)
//
#include <hip/hip_runtime.h>
#include <cfloat>
#include <cmath>
#include <stdint.h>

#define N 8192
#define D 512
#define K 16
#define SLICES 8
#define SLW 1024   // slice width (cols)
#define TB 128     // gemm block tile
#define KC 64      // k chunk (bf16 elems) = 8 granules of 16B
#define NCH (D / KC)
#define NPART (SLICES * K)   // 128 partial entries per row
#define FB 64      // final-reduce blocks

typedef __bf16 bf16x8 __attribute__((ext_vector_type(8)));
typedef __bf16 bf16x4 __attribute__((ext_vector_type(4)));
typedef float  f32x4  __attribute__((ext_vector_type(4)));

// ---------------- kernel 1: cast to bf16 + row squared norms (fp32) ----------
__global__ __launch_bounds__(256)
void k_cast_sqnorm(const float* __restrict__ emb, float* __restrict__ sq,
                   __bf16* __restrict__ embh) {
    int row = blockIdx.x * 4 + (threadIdx.x >> 6);
    int lane = threadIdx.x & 63;
    const float4* e = (const float4*)(emb + (size_t)row * D);
    float s = 0.f;
    #pragma unroll
    for (int c = 0; c < 2; c++) {
        float4 v = e[lane + 64 * c];
        s += v.x * v.x + v.y * v.y + v.z * v.z + v.w * v.w;
        bf16x4 h = { (__bf16)v.x, (__bf16)v.y, (__bf16)v.z, (__bf16)v.w };
        *(bf16x4*)&embh[(size_t)row * D + (size_t)(lane + 64 * c) * 4] = h;
    }
    for (int off = 32; off; off >>= 1) s += __shfl_down(s, off, 64);
    if (lane == 0) sq[row] = s;
}

// ---------------- kernel 2: pure MFMA distance GEMM (one 1024-col slice) -----
// grid 512: rt = bid>>3 (row tile), ct = bid&7 (col tile within slice).
// 4 waves, wave tile 64x64 = 4x4 of mfma_16x16x32_bf16 (8 ds_read_b128 per
// 16 MFMA - m97 ratio). Epilogue: d2 = sqA[r] + sqB[c] - 2*dot -> f32 slice.
// No selection state in registers -> no spill (the R2-R9 fused designs all
// spilled ~100 MB of scratch).
__global__ __launch_bounds__(256)
void k_gemm(const __bf16* __restrict__ embh, const float* __restrict__ sq,
            float* __restrict__ d2buf, int jsb) {
    __shared__ __align__(16) uint4 As4[TB * 8];      // 16 KB
    __shared__ __align__(16) uint4 Bs4[TB * 8];      // 16 KB
    __shared__ float sqA[TB], sqB[TB];

    const int t  = threadIdx.x;
    const int rt = blockIdx.x >> 3, ct = blockIdx.x & 7;
    const int ib = rt * TB;
    const int jb = jsb + ct * TB;
    const int lane = t & 63, w = t >> 6;
    const int wr = (w >> 1) * 64, wc = (w & 1) * 64;
    const int l15 = lane & 15, q4 = lane >> 4;
    const int sr = t >> 3, sg = t & 7;   // staging: row, 16B granule

    if (t < TB) { sqA[t] = sq[ib + t]; sqB[t] = sq[jb + t]; }

    f32x4 acc[4][4];
    #pragma unroll
    for (int mi = 0; mi < 4; mi++)
        #pragma unroll
        for (int ni = 0; ni < 4; ni++) { f32x4 z = {}; acc[mi][ni] = z; }

    // stage chunk 0 (swizzled: granule c ^= row&7)
    #pragma unroll
    for (int q = 0; q < 4; q++) {
        int row = sr + 32 * q;
        As4[row * 8 + (sg ^ (row & 7))] = *(const uint4*)&embh[(size_t)(ib + row) * D + sg * 8];
        Bs4[row * 8 + (sg ^ (row & 7))] = *(const uint4*)&embh[(size_t)(jb + row) * D + sg * 8];
    }
    __syncthreads();

    uint4 pfA[4], pfB[4];
    #pragma unroll 1
    for (int kc = 0; kc < NCH; kc++) {
        if (kc + 1 < NCH) {                // register prefetch of next chunk
            int k0 = (kc + 1) * KC;
            #pragma unroll
            for (int q = 0; q < 4; q++) {
                int row = sr + 32 * q;
                pfA[q] = *(const uint4*)&embh[(size_t)(ib + row) * D + k0 + sg * 8];
                pfB[q] = *(const uint4*)&embh[(size_t)(jb + row) * D + k0 + sg * 8];
            }
        }
        #pragma unroll
        for (int kk = 0; kk < 2; kk++) {   // two 32-deep MFMA steps per chunk
            int c = kk * 4 + q4;           // granule holding this lane's k-slice
            bf16x8 af[4], bf[4];
            #pragma unroll
            for (int mi = 0; mi < 4; mi++) {
                int row = wr + mi * 16 + l15;
                af[mi] = __builtin_bit_cast(bf16x8, As4[row * 8 + (c ^ (row & 7))]);
            }
            #pragma unroll
            for (int ni = 0; ni < 4; ni++) {
                int row = wc + ni * 16 + l15;
                bf[ni] = __builtin_bit_cast(bf16x8, Bs4[row * 8 + (c ^ (row & 7))]);
            }
            #pragma unroll
            for (int mi = 0; mi < 4; mi++)
                #pragma unroll
                for (int ni = 0; ni < 4; ni++)
                    acc[mi][ni] = __builtin_amdgcn_mfma_f32_16x16x32_bf16(
                        af[mi], bf[ni], acc[mi][ni], 0, 0, 0);
        }
        __syncthreads();                   // all waves done reading As/Bs
        if (kc + 1 < NCH) {
            #pragma unroll
            for (int q = 0; q < 4; q++) {
                int row = sr + 32 * q;
                As4[row * 8 + (sg ^ (row & 7))] = pfA[q];
                Bs4[row * 8 + (sg ^ (row & 7))] = pfB[q];
            }
            __syncthreads();               // next chunk visible
        }
    }

    // epilogue: C layout col=lane&15, row=(lane>>4)*4+reg (m89-verified)
    #pragma unroll
    for (int mi = 0; mi < 4; mi++)
        #pragma unroll
        for (int ni = 0; ni < 4; ni++)
            #pragma unroll
            for (int reg = 0; reg < 4; reg++) {
                int r_l = wr + mi * 16 + q4 * 4 + reg;
                int c_l = wc + ni * 16 + l15;
                float v = sqA[r_l] + sqB[c_l] - 2.f * acc[mi][ni][reg];
                d2buf[(size_t)(ib + r_l) * SLW + ct * TB + c_l] = v;
            }
}

// ---------------- kernel 3: top-16 select over one slice ---------------------
// grid 128: 64 rows/block, 4 threads/row, each scans 256 cols (64x b128,
// granule-interleaved for coalescing). Register top-16 (static-indexed
// replace-first-equal), then LDS merge 4x16 -> 16 per row (stride 65).
__global__ __launch_bounds__(256)
void k_select(const float* __restrict__ d2buf, float* __restrict__ pd2,
              int* __restrict__ pidx, int sl) {
    __shared__ float mD[64 * 65];          // 16.6 KB
    __shared__ float mI[64 * 65];          // idx as float bits
    const int t = threadIdx.x;
    const int lr = t >> 2, q = t & 3;
    const int row = blockIdx.x * 64 + lr;
    const int jsb = sl * SLW;
    const float* pr = d2buf + (size_t)row * SLW;

    float ld[K]; int li[K]; float kth = FLT_MAX;
    #pragma unroll
    for (int s = 0; s < K; s++) { ld[s] = FLT_MAX; li[s] = 0; }

    #pragma unroll 4
    for (int i = 0; i < 64; i++) {
        int g = q + 4 * i;
        f32x4 v4 = *(const f32x4*)&pr[g * 4];
        #pragma unroll
        for (int e = 0; e < 4; e++) {
            float v = v4[e];
            if (v < kth) {
                int j = jsb + g * 4 + e;
                if (j != row) {
                    bool rep = false;
                    #pragma unroll
                    for (int s = 0; s < K; s++)
                        if (!rep && ld[s] == kth) { ld[s] = v; li[s] = j; rep = true; }
                    float mx = ld[0];
                    #pragma unroll
                    for (int s = 1; s < K; s++) mx = fmaxf(mx, ld[s]);
                    kth = mx;
                }
            }
        }
    }

    #pragma unroll
    for (int s = 0; s < K; s++) {
        mD[lr * 65 + q * 16 + s] = ld[s];
        mI[lr * 65 + q * 16 + s] = __int_as_float(li[s]);
    }
    __syncthreads();
    if (t < 64) {
        const int orow = blockIdx.x * 64 + t;
        float bd[K]; int bi[K]; float kmx = FLT_MAX;
        #pragma unroll
        for (int s = 0; s < K; s++) { bd[s] = FLT_MAX; bi[s] = 0; }
        #pragma unroll 1
        for (int s = 0; s < 64; s++) {
            float d2 = mD[t * 65 + s];
            if (d2 < kmx) {
                int j = __float_as_int(mI[t * 65 + s]);
                bool rep = false;
                #pragma unroll
                for (int u = 0; u < K; u++)
                    if (!rep && bd[u] == kmx) { bd[u] = d2; bi[u] = j; rep = true; }
                float mx = bd[0];
                #pragma unroll
                for (int u = 1; u < K; u++) mx = fmaxf(mx, bd[u]);
                kmx = mx;
            }
        }
        #pragma unroll
        for (int s = 0; s < K; s++) {
            pd2[(size_t)orow * NPART + sl * K + s]  = bd[s];
            pidx[(size_t)orow * NPART + sl * K + s] = bi[s];
        }
    }
}

// ---------------- kernel 4: merge 8 partial lists per row --------------------
__global__ __launch_bounds__(256)
void k_merge(const float* __restrict__ pd2, const int* __restrict__ pidx,
             int* __restrict__ knn, float* __restrict__ row_sum) {
    int row = blockIdx.x * 256 + threadIdx.x;
    float bd[K]; int bi[K]; float kmx = FLT_MAX;
    #pragma unroll
    for (int s = 0; s < K; s++) { bd[s] = FLT_MAX; bi[s] = 0; }
    const float* pr = pd2 + (size_t)row * NPART;
    const int*   pi = pidx + (size_t)row * NPART;
    #pragma unroll 1
    for (int s = 0; s < NPART; s++) {
        float d2 = pr[s];
        if (d2 < kmx) {
            int j = pi[s];
            bool rep = false;
            #pragma unroll
            for (int u = 0; u < K; u++)
                if (!rep && bd[u] == kmx) { bd[u] = d2; bi[u] = j; rep = true; }
            float mx = bd[0];
            #pragma unroll
            for (int u = 1; u < K; u++) mx = fmaxf(mx, bd[u]);
            kmx = mx;
        }
    }
    float s = 0.f;
    #pragma unroll
    for (int u = 0; u < K; u++) {
        float d2 = bd[u];
        s += (d2 > 0.f) ? sqrtf(fmaxf(d2, 1e-12f)) : 0.f;
        knn[(size_t)row * K + u] = bi[u];
    }
    row_sum[row] = s;
}

// ---------------- kernel 5: per-row curvature via MFMA Gram ------------------
__global__ __launch_bounds__(256, 2)
void k_curv(const __bf16* __restrict__ embh, const int* __restrict__ knn_idx,
            const float* __restrict__ row_sum, const float* __restrict__ ref_curv,
            float* __restrict__ curv_err) {
    __shared__ uint4 nb4[4][K * 64];       // 4 x 16 KB, swizzled
    __shared__ float Gm[4][K][K + 1];
    const int t = threadIdx.x;
    const int w = t >> 6, lane = t & 63;
    const int i = blockIdx.x * 4 + w;
    const int r = lane >> 2, qt = lane & 3;

    const int nrow = knn_idx[(size_t)i * K + r];
    const uint4* src = (const uint4*)(embh + (size_t)nrow * D) + qt * 16;
    #pragma unroll
    for (int it = 0; it < 16; it++) {
        int c = qt * 16 + it;
        nb4[w][r * 64 + (c ^ (r & 7))] = src[it];
    }
    __syncthreads();

    f32x4 acc = {};
    const int m = lane & 15, q4 = lane >> 4;
    #pragma unroll
    for (int ck = 0; ck < 16; ck++) {
        int c = ck * 4 + q4;
        bf16x8 fr = __builtin_bit_cast(bf16x8, nb4[w][m * 64 + (c ^ (m & 7))]);
        acc = __builtin_amdgcn_mfma_f32_16x16x32_bf16(fr, fr, acc, 0, 0, 0);
    }
    #pragma unroll
    for (int reg = 0; reg < 4; reg++)
        Gm[w][q4 * 4 + reg][m] = acc[reg];
    __syncthreads();

    float s = 0.f;
    #pragma unroll
    for (int qq = 0; qq < 4; qq++) {
        int cell = lane + 64 * qq;
        int j = cell >> 4, l = cell & 15;
        float d2 = Gm[w][j][j] + Gm[w][l][l] - 2.f * Gm[w][j][l];
        s += (d2 > 0.f) ? sqrtf(fmaxf(d2, 1e-12f)) : 0.f;
    }
    for (int off = 32; off; off >>= 1) s += __shfl_down(s, off, 64);
    if (lane == 0) {
        float inter_mean = s * 0.5f / 120.f;
        float avg = row_sum[i] / 16.f;
        float curv = inter_mean / (avg + 1e-8f);
        float diff = curv - ref_curv[i];
        curv_err[i] = diff * diff;
    }
}

// ---------------- kernel 6a: partial reduce (64 blocks) ----------------------
__global__ __launch_bounds__(256)
void k_partial(const float* __restrict__ curv_err, const float* __restrict__ row_sum,
               const float* __restrict__ ref_dist, float* __restrict__ partials) {
    const int t = threadIdx.x, b = blockIdx.x;
    float s1 = 0.f, s2 = 0.f, s3 = 0.f;
    for (int i = b * 256 + t; i < N; i += FB * 256) { s1 += curv_err[i]; s2 += row_sum[i]; }
    for (int i = b * 256 + t; i < N * K; i += FB * 256) s3 += ref_dist[i];
    for (int off = 32; off; off >>= 1) {
        s1 += __shfl_down(s1, off, 64);
        s2 += __shfl_down(s2, off, 64);
        s3 += __shfl_down(s3, off, 64);
    }
    __shared__ float a1[4], a2[4], a3[4];
    int w = t >> 6, lane = t & 63;
    if (lane == 0) { a1[w] = s1; a2[w] = s2; a3[w] = s3; }
    __syncthreads();
    if (t == 0) {
        partials[b * 3 + 0] = a1[0] + a1[1] + a1[2] + a1[3];
        partials[b * 3 + 1] = a2[0] + a2[1] + a2[2] + a2[3];
        partials[b * 3 + 2] = a3[0] + a3[1] + a3[2] + a3[3];
    }
}

// ---------------- kernel 6b: final scalar ------------------------------------
__global__ __launch_bounds__(64)
void k_final2(const float* __restrict__ partials, float* __restrict__ out) {
    const int t = threadIdx.x;
    float s1 = partials[t * 3 + 0];
    float s2 = partials[t * 3 + 1];
    float s3 = partials[t * 3 + 2];
    for (int off = 32; off; off >>= 1) {
        s1 += __shfl_down(s1, off, 64);
        s2 += __shfl_down(s2, off, 64);
        s3 += __shfl_down(s3, off, 64);
    }
    if (t == 0) {
        float curv_loss = s1 / (float)N;
        float dm = s2 / (float)(N * K);
        float rm = s3 / (float)(N * K);
        float d = dm - rm;
        out[0] = curv_loss + 0.1f * d * d;
    }
}

extern "C" void kernel_launch(void* const* d_in, const int* in_sizes, int n_in,
                              void* d_out, int out_size, void* d_ws, size_t ws_size,
                              hipStream_t stream) {
    const float* emb      = (const float*)d_in[0];
    const float* ref_curv = (const float*)d_in[1];
    const float* ref_dist = (const float*)d_in[2];
    float* out = (float*)d_out;

    float*  sq       = (float*)d_ws;                       // N
    float*  row_sum  = sq + N;                             // N
    float*  curv_err = row_sum + N;                        // N
    float*  partials = curv_err + N;                       // 3*FB (192, pad to 256)
    float*  pd2      = partials + 256;                     // N*128
    int*    pidx     = (int*)(pd2 + (size_t)N * NPART);    // N*128
    int*    knn      = pidx + (size_t)N * NPART;           // N*K
    __bf16* embh     = (__bf16*)(knn + (size_t)N * K);     // N*D bf16 (8 MB)
    float*  d2buf    = (float*)(embh + (size_t)N * D);     // N*SLW f32 (33.5 MB)

    k_cast_sqnorm<<<N / 4, 256, 0, stream>>>(emb, sq, embh);
    for (int sl = 0; sl < SLICES; sl++) {
        k_gemm<<<(N / TB) * 8, 256, 0, stream>>>(embh, sq, d2buf, sl * SLW);
        k_select<<<N / 64, 256, 0, stream>>>(d2buf, pd2, pidx, sl);
    }
    k_merge<<<N / 256, 256, 0, stream>>>(pd2, pidx, knn, row_sum);
    k_curv<<<N / 4, 256, 0, stream>>>(embh, knn, row_sum, ref_curv, curv_err);
    k_partial<<<FB, 256, 0, stream>>>(curv_err, row_sum, ref_dist, partials);
    k_final2<<<1, 64, 0, stream>>>(partials, out);
}